// Round 2
// 666.864 us; speedup vs baseline: 1.1148x; 1.1148x over previous
//
#include <hip/hip_runtime.h>
#include <hip/hip_fp16.h>
#include <stdint.h>

// ---------------------------------------------------------------------------
// GraphConv (planetoid-gcn-residual):
//   h   = norm * (x @ W.T + bias),  norm = rsqrt(1+deg)
//   out = norm * (spmm_add(adj,h) + h)
// R3 changes vs R2 (743.6 us):
//  - deg_kernel + scatter atomics merged into ONE atomic pass (rank_kernel);
//    scatter is now atomic-free. deg array removed (norm from rs diffs).
//  - gemm LDS staging writes were a ~32-way bank conflict (k_step stride
//    1024B, q stride 256B == 0 mod 128B). XOR swizzle on write+read -> 2-way.
//  - agg split into two half-feature dispatches (cols [0,128),[128,256)):
//    same total gather traffic, but unmasks second-tier kernels in top-5.
// R4: identical resubmit of R3 (previous round hit GPUAcquisitionTimeout;
//     no counters came back, so no evidence to justify a change).
// ---------------------------------------------------------------------------

#define THREADS 256

typedef _Float16 half8 __attribute__((ext_vector_type(8)));
typedef float floatx4 __attribute__((ext_vector_type(4)));

// ---------------- rank pass: one atomic per edge, rank stored ----------------
__global__ void rank_kernel(const int* __restrict__ rows, int* __restrict__ cnt,
                            int* __restrict__ rank, int E) {
    int e = (blockIdx.x * THREADS + threadIdx.x) * 4;
    if (e + 3 < E) {
        int4 r4 = *(const int4*)(rows + e);
        int4 k;
        k.x = atomicAdd(&cnt[r4.x], 1);
        k.y = atomicAdd(&cnt[r4.y], 1);
        k.z = atomicAdd(&cnt[r4.z], 1);
        k.w = atomicAdd(&cnt[r4.w], 1);
        *(int4*)(rank + e) = k;
    } else {
        for (int i = e; i < E && i < e + 4; ++i)
            rank[i] = atomicAdd(&cnt[rows[i]], 1);
    }
}

// ---------------- 3-kernel exclusive scan over cnt[0..n) ----------------
__global__ void scanA(const int* __restrict__ cnt, int* __restrict__ rs,
                      int* __restrict__ bsums, int n) {
    __shared__ int s[THREADS];
    int tid  = threadIdx.x;
    int base = blockIdx.x * 1024 + tid * 4;
    int v0 = (base + 0 < n) ? cnt[base + 0] : 0;
    int v1 = (base + 1 < n) ? cnt[base + 1] : 0;
    int v2 = (base + 2 < n) ? cnt[base + 2] : 0;
    int v3 = (base + 3 < n) ? cnt[base + 3] : 0;
    int sum = v0 + v1 + v2 + v3;
    s[tid] = sum;
    __syncthreads();
    for (int off = 1; off < THREADS; off <<= 1) {
        int t = (tid >= off) ? s[tid - off] : 0;
        __syncthreads();
        s[tid] += t;
        __syncthreads();
    }
    int run = s[tid] - sum;
    if (base + 0 < n) rs[base + 0] = run;  run += v0;
    if (base + 1 < n) rs[base + 1] = run;  run += v1;
    if (base + 2 < n) rs[base + 2] = run;  run += v2;
    if (base + 3 < n) rs[base + 3] = run;
    if (tid == THREADS - 1) bsums[blockIdx.x] = s[THREADS - 1];
}

__global__ void scanB(int* __restrict__ bsums, int nb) {
    __shared__ int s[THREADS];
    int tid = threadIdx.x;
    int v = (tid < nb) ? bsums[tid] : 0;
    s[tid] = v;
    __syncthreads();
    for (int off = 1; off < THREADS; off <<= 1) {
        int t = (tid >= off) ? s[tid - off] : 0;
        __syncthreads();
        s[tid] += t;
        __syncthreads();
    }
    if (tid < nb) bsums[tid] = s[tid] - v;
}

__global__ void scanC(int* __restrict__ rs, const int* __restrict__ bsums, int n, int E) {
    int tid  = threadIdx.x;
    int base = blockIdx.x * 1024 + tid * 4;
    int add  = bsums[blockIdx.x];
    if (base + 0 < n) rs[base + 0] += add;
    if (base + 1 < n) rs[base + 1] += add;
    if (base + 2 < n) rs[base + 2] += add;
    if (base + 3 < n) rs[base + 3] += add;
    if (blockIdx.x == 0 && tid == 0) rs[n] = E;
}

// ---------------- atomic-free scatter using precomputed ranks ----------------
__global__ void scatter2(const int* __restrict__ rows, const int* __restrict__ cols,
                         const int* __restrict__ rank, const int* __restrict__ rs,
                         int* __restrict__ csr_col, int E) {
    int e = (blockIdx.x * THREADS + threadIdx.x) * 4;
    if (e + 3 < E) {
        int4 r4 = *(const int4*)(rows + e);
        int4 c4 = *(const int4*)(cols + e);
        int4 k4 = *(const int4*)(rank + e);
        csr_col[rs[r4.x] + k4.x] = c4.x;
        csr_col[rs[r4.y] + k4.y] = c4.y;
        csr_col[rs[r4.z] + k4.z] = c4.z;
        csr_col[rs[r4.w] + k4.w] = c4.w;
    } else {
        for (int i = e; i < E && i < e + 4; ++i)
            csr_col[rs[rows[i]] + rank[i]] = cols[i];
    }
}

// ---------------- W -> f16 B-fragment swizzle ----------------
__global__ void make_bswz(const float* __restrict__ W, half8* __restrict__ Bswz) {
    int t = blockIdx.x * THREADS + threadIdx.x;   // 8192 entries
    int n_tile = t >> 9;
    int k_step = (t >> 6) & 7;
    int lane   = t & 63;
    int q = lane >> 4, m16 = lane & 15;
    const float* src = W + (size_t)(n_tile * 16 + m16) * 256 + k_step * 32 + q * 8;
    half8 h;
#pragma unroll
    for (int j = 0; j < 8; j++) h[j] = (_Float16)src[j];
    Bswz[t] = h;
}

// LDS byte-address swizzle: spread k_step (bits 10-12) and q-parity (bit 8)
// into bits 4-7 so staging writes hit all banks (was ~32-way conflict).
__device__ __forceinline__ int As_swz(int b) {
    return b ^ ((((b >> 10) & 7) ^ (((b >> 8) & 1) << 3)) << 4);
}

// ---------------- f16 MFMA GEMM + bias + norm scale ----------------
// Block: 256 thr = 4 waves. Tile: 64 rows x 256 cols; wave w -> cols [64w,64w+64).
__global__ __launch_bounds__(THREADS) void gemm_mfma(
    const float* __restrict__ x, const half8* __restrict__ Bswz,
    const float* __restrict__ bias, const int* __restrict__ rs,
    _Float16* __restrict__ h16, int n) {
    __shared__ _Float16 As[4 * 8 * 64 * 8];   // 32 KB, A-frag layout (swizzled)
    int tid  = threadIdx.x;
    int row0 = blockIdx.x * 64;

    // stage x tile fp32 -> f16 into (swizzled) A-frag layout
#pragma unroll
    for (int i = 0; i < 16; i++) {
        int flat = i * THREADS + tid;
        int r  = flat >> 6;         // 0..63 row in tile
        int k  = (flat & 63) * 4;   // 0..252 step 4
        float4 v;
        if (row0 + r < n) v = *(const float4*)(x + (size_t)(row0 + r) * 256 + k);
        else { v.x = 0.f; v.y = 0.f; v.z = 0.f; v.w = 0.f; }
        int m_sub  = r >> 4;
        int k_step = k >> 5;
        int q      = (k >> 3) & 3;
        int j      = k & 7;         // 0 or 4
        int lane_w = (r & 15) + (q << 4);
        int entry  = (m_sub * 8 + k_step) * 64 + lane_w;
        union { _Float16 h[4]; uint2 u; } pk;
        pk.h[0] = (_Float16)v.x; pk.h[1] = (_Float16)v.y;
        pk.h[2] = (_Float16)v.z; pk.h[3] = (_Float16)v.w;
        *(uint2*)((char*)As + As_swz(entry * 16 + (j << 1))) = pk.u;
    }
    __syncthreads();

    int w    = tid >> 6;    // wave id = n-slice
    int lane = tid & 63;

    floatx4 acc[4][4];
#pragma unroll
    for (int ms = 0; ms < 4; ms++)
#pragma unroll
        for (int nn = 0; nn < 4; nn++) {
            acc[ms][nn][0] = 0.f; acc[ms][nn][1] = 0.f;
            acc[ms][nn][2] = 0.f; acc[ms][nn][3] = 0.f;
        }

    for (int ks = 0; ks < 8; ks++) {
        half8 bfrag[4];
#pragma unroll
        for (int nn = 0; nn < 4; nn++)
            bfrag[nn] = Bswz[((w * 4 + nn) * 8 + ks) * 64 + lane];
        half8 afrag[4];
#pragma unroll
        for (int ms = 0; ms < 4; ms++)
            afrag[ms] = *(const half8*)((char*)As +
                            As_swz(((ms * 8 + ks) * 64 + lane) * 16));
#pragma unroll
        for (int ms = 0; ms < 4; ms++)
#pragma unroll
            for (int nn = 0; nn < 4; nn++)
                acc[ms][nn] = __builtin_amdgcn_mfma_f32_16x16x32_f16(
                    afrag[ms], bfrag[nn], acc[ms][nn], 0, 0, 0);
    }

    // epilogue: C/D layout col=lane&15, row=(lane>>4)*4+i
    int rgrp = lane >> 4;
    int cl   = lane & 15;
#pragma unroll
    for (int ms = 0; ms < 4; ms++) {
        int rbase = row0 + ms * 16 + rgrp * 4;
        float nrm[4];
#pragma unroll
        for (int i = 0; i < 4; i++) {
            int r = rbase + i;
            nrm[i] = (r < n) ? rsqrtf(1.0f + (float)(rs[r + 1] - rs[r])) : 0.f;
        }
#pragma unroll
        for (int nn = 0; nn < 4; nn++) {
            int col = w * 64 + nn * 16 + cl;
            float bb = bias[col];
#pragma unroll
            for (int i = 0; i < 4; i++) {
                int r = rbase + i;
                if (r < n)
                    h16[(size_t)r * 256 + col] =
                        (_Float16)((acc[ms][nn][i] + bb) * nrm[i]);
            }
        }
    }
}

// ---------------- aggregation over one feature half (128 cols) ----------------
// Wave per row; quarter-wave (16 lanes x 16B) per edge, 4 edges in flight.
__global__ __launch_bounds__(THREADS) void agg_half(
    const _Float16* __restrict__ h16, const int* __restrict__ csr_col,
    const int* __restrict__ rs, float* __restrict__ out, int n, int halfsel) {
    int row = blockIdx.x * 4 + (threadIdx.x >> 6);
    if (row >= n) return;
    int lane = threadIdx.x & 63;
    int g    = lane >> 4;            // edge group 0..3
    int l16  = lane & 15;
    int off  = halfsel * 128 + l16 * 8;   // 8 f16 cols per lane
    const _Float16* hb = h16 + off;

    int s   = rs[row];
    int end = rs[row + 1];

    float acc[8] = {0.f, 0.f, 0.f, 0.f, 0.f, 0.f, 0.f, 0.f};
    if (g == 0) {   // residual h_scaled[row] for this half
        half8 v = *(const half8*)(hb + (size_t)row * 256);
#pragma unroll
        for (int j = 0; j < 8; j++) acc[j] = (float)v[j];
    }

    int e = s + g;   // group g takes edges s+g, s+g+4, ...
    for (; e + 4 < end; e += 8) {
        int c0 = csr_col[e];
        int c1 = csr_col[e + 4];
        half8 v0 = *(const half8*)(hb + (size_t)c0 * 256);
        half8 v1 = *(const half8*)(hb + (size_t)c1 * 256);
#pragma unroll
        for (int j = 0; j < 8; j++) acc[j] += (float)v0[j] + (float)v1[j];
    }
    for (; e < end; e += 4) {
        int c = csr_col[e];
        half8 v = *(const half8*)(hb + (size_t)c * 256);
#pragma unroll
        for (int j = 0; j < 8; j++) acc[j] += (float)v[j];
    }

    // cross-group reduction: 4 groups -> group 0
#pragma unroll
    for (int j = 0; j < 8; j++) acc[j] += __shfl_down(acc[j], 32);
#pragma unroll
    for (int j = 0; j < 8; j++) acc[j] += __shfl_down(acc[j], 16);

    if (g == 0) {
        float nrm = rsqrtf(1.0f + (float)(end - s));
        float4 o0, o1;
        o0.x = acc[0] * nrm; o0.y = acc[1] * nrm; o0.z = acc[2] * nrm; o0.w = acc[3] * nrm;
        o1.x = acc[4] * nrm; o1.y = acc[5] * nrm; o1.z = acc[6] * nrm; o1.w = acc[7] * nrm;
        float* dst = out + (size_t)row * 256 + off;
        *(float4*)dst       = o0;
        *(float4*)(dst + 4) = o1;
    }
}

// ---------------------------------------------------------------------------
extern "C" void kernel_launch(void* const* d_in, const int* in_sizes, int n_in,
                              void* d_out, int out_size, void* d_ws, size_t ws_size,
                              hipStream_t stream) {
    const float* x    = (const float*)d_in[0];
    const float* W    = (const float*)d_in[1];
    const float* bias = (const float*)d_in[2];
    const int*   rows = (const int*)d_in[3];
    const int*   cols = (const int*)d_in[4];

    const int D = 256;
    int n = in_sizes[0] / D;    // 100000
    int E = in_sizes[3];        // 3200000

    // ---- workspace carve ----
    char* p = (char*)d_ws;
    auto alignup = [](size_t v) { return (v + 255) & ~(size_t)255; };
    _Float16* h16 = (_Float16*)p; p += alignup((size_t)n * D * sizeof(_Float16)); // 51.2 MB
    int*   cnt    = (int*)p;    p += alignup((size_t)n * sizeof(int));
    int*   rs     = (int*)p;    p += alignup((size_t)(n + 1) * sizeof(int));
    int*   bsums  = (int*)p;    p += alignup((size_t)1024);
    int*   csr    = (int*)p;    p += alignup((size_t)E * sizeof(int));            // 12.8 MB
    half8* Bswz   = (half8*)p;  p += alignup((size_t)8192 * sizeof(half8));       // 128 KB

    // rank[] overlays the h16 region (12.8 MB << 51.2 MB); h16 is written
    // by gemm only AFTER scatter2 has consumed rank.
    int* rank = (int*)h16;

    hipMemsetAsync(cnt, 0, (size_t)n * sizeof(int), stream);

    int e4blocks = ((E + 3) / 4 + THREADS - 1) / THREADS;   // 3125
    rank_kernel<<<e4blocks, THREADS, 0, stream>>>(rows, cnt, rank, E);

    int nb = (n + 1023) / 1024;  // 98 <= 256
    scanA<<<nb, THREADS, 0, stream>>>(cnt, rs, bsums, n);
    scanB<<<1, THREADS, 0, stream>>>(bsums, nb);
    scanC<<<nb, THREADS, 0, stream>>>(rs, bsums, n, E);

    scatter2<<<e4blocks, THREADS, 0, stream>>>(rows, cols, rank, rs, csr, E);

    make_bswz<<<32, THREADS, 0, stream>>>(W, Bswz);

    int gblocks = (n + 63) / 64;   // 1563
    gemm_mfma<<<gblocks, THREADS, 0, stream>>>(x, Bswz, bias, rs, h16, n);

    int ablocks = (n + 3) / 4;     // 25000
    agg_half<<<ablocks, THREADS, 0, stream>>>(h16, csr, rs, (float*)d_out, n, 0);
    agg_half<<<ablocks, THREADS, 0, stream>>>(h16, csr, rs, (float*)d_out, n, 1);
}